// Round 7
// baseline (220.913 us; speedup 1.0000x reference)
//
#include <hip/hip_runtime.h>
#include <hip/hip_bf16.h>

#define NT 4096
#define HD 2048
#define NE 16
#define ID 512
#define TWO_I 1024
#define PITCH 72     // padded bf16 B-tile pitch (144B) for conflict-free b128 frag reads
#define MAXITEMS 47  // worst case: ceil(4081/128)=32 + 15 singleton experts

typedef __attribute__((ext_vector_type(8))) short bf16x8_t;
typedef __attribute__((ext_vector_type(4))) float f32x4_t;

__device__ __forceinline__ unsigned short f2bf(float f) {
  union { float f; unsigned int u; } v; v.f = f;
  unsigned int r = v.u + 0x7fffu + ((v.u >> 16) & 1u);
  return (unsigned short)(r >> 16);
}
__device__ __forceinline__ unsigned pk2(unsigned short a, unsigned short b) {
  return (unsigned)a | ((unsigned)b << 16);
}
// async global->LDS, 16B per lane; LDS dest = wave-uniform base + lane*16
__device__ __forceinline__ void gl_lds16(const void* g, void* l) {
  __builtin_amdgcn_global_load_lds(
      (const __attribute__((address_space(1))) unsigned int*)g,
      (__attribute__((address_space(3))) unsigned int*)l, 16, 0, 0);
}

// ---------------- cast x (f32 -> bf16) ----------------
__global__ void k_cast_x(const float* __restrict__ x, unsigned short* __restrict__ xb) {
  size_t i = ((size_t)blockIdx.x * 256 + threadIdx.x) * 8;
  float4 a = *(const float4*)(x + i);
  float4 b = *(const float4*)(x + i + 4);
  uint4 pk;
  pk.x = pk2(f2bf(a.x), f2bf(a.y)); pk.y = pk2(f2bf(a.z), f2bf(a.w));
  pk.z = pk2(f2bf(b.x), f2bf(b.y)); pk.w = pk2(f2bf(b.z), f2bf(b.w));
  *(uint4*)(xb + i) = pk;
}

// ---------------- routing ----------------
__global__ void k_route(const float* __restrict__ mu, const int* __restrict__ tok,
                        const float* __restrict__ wr, int* __restrict__ eid) {
  int t = blockIdx.x;
  int tid = threadIdx.x;
  float p[NE];
#pragma unroll
  for (int e = 0; e < NE; ++e) p[e] = 0.f;
  const float* m = mu + (size_t)t * HD;
  for (int h = tid; h < HD; h += 256) {
    float mv = m[h];
#pragma unroll
    for (int e = 0; e < NE; ++e) p[e] += mv * wr[e * HD + h];
  }
#pragma unroll
  for (int e = 0; e < NE; ++e) {
    float v = p[e];
#pragma unroll
    for (int s = 32; s; s >>= 1) v += __shfl_xor(v, s, 64);
    p[e] = v;
  }
  __shared__ float red[4][NE];
  int lane = tid & 63, wv = tid >> 6;
  if (lane == 0) {
#pragma unroll
    for (int e = 0; e < NE; ++e) red[wv][e] = p[e];
  }
  __syncthreads();
  if (tid == 0) {
    int tk = tok[t];
    if (tk < 0) tk = 0;
    if (tk > 31999) tk = 31999;
    int base = tk & 15;
    float best = -3.0e38f; int bi = 0;
    for (int e = 0; e < NE; ++e) {
      float v = red[0][e] + red[1][e] + red[2][e] + red[3][e];
      if (e == base) v += 10.0f;
      if (v > best) { best = v; bi = e; }
    }
    eid[t] = bi;
  }
}

// ---------------- bucket tokens + worklist ----------------
__global__ void k_init(int* counts, int* cursors) {
  int i = threadIdx.x;
  if (i < NE) { counts[i] = 0; cursors[i] = 0; }
}
__global__ void k_hist(const int* __restrict__ eid, int* __restrict__ counts) {
  int t = blockIdx.x * 256 + threadIdx.x;
  if (t < NT) atomicAdd(&counts[eid[t]], 1);
}
__global__ void k_scan(const int* __restrict__ counts, int* __restrict__ offsets,
                       int* __restrict__ cursors, int* __restrict__ wk) {
  if (threadIdx.x == 0) {
    int s = 0;
    for (int e = 0; e < NE; ++e) { offsets[e] = s; cursors[e] = s; s += counts[e]; }
    offsets[NE] = s;
    int n = 0;
    for (int e = 0; e < NE; ++e) {
      int tiles = (counts[e] + 127) >> 7;
      for (int m = 0; m < tiles; ++m) { wk[n++] = e | (m << 8); }
    }
    wk[MAXITEMS] = n;
  }
}
__global__ void k_scatter(const int* __restrict__ eid, int* __restrict__ cursors,
                          int* __restrict__ tlist) {
  int t = blockIdx.x * 256 + threadIdx.x;
  if (t < NT) {
    int e = eid[t];
    int pos = atomicAdd(&cursors[e], 1);
    tlist[pos] = t;
  }
}

// ---------------- gemm1: h = silu(x@Wg) * (x@Wu) ----------------
// async global_load_lds staging (A bf16 swizzled, B f32 natural) + counted vmcnt
// + LDS transpose/convert pass for B. M=128 tok x 32 h-cols per block.
__global__ __launch_bounds__(256, 2) void k_gemm1(
    const unsigned short* __restrict__ xb, const float* __restrict__ gup,
    const int* __restrict__ offsets, const int* __restrict__ tlist,
    const int* __restrict__ wk, unsigned short* __restrict__ hbuf) {
  int item = blockIdx.y;
  if (item >= wk[MAXITEMS]) return;
  int w = wk[item];
  int e = w & 255, tb = (w >> 8) * 128;
  int off = offsets[e], cnt = offsets[e + 1] - off;
  int c0 = blockIdx.x * 32;

  __shared__ unsigned short Abuf[2][128 * 64]; // [row][k] bf16, chunk-swizzled
  __shared__ float Bbuf[2][64 * 64];           // [k][col] f32, natural
  __shared__ unsigned short Pbuf[64 * PITCH];  // [col][k] bf16, padded
  __shared__ int ltok[128];

  int tid = threadIdx.x, lane = tid & 63, wv = tid >> 6;
  if (tid < 128) { int r = tb + tid; if (r > cnt - 1) r = cnt - 1; ltok[tid] = tlist[off + r]; }
  __syncthreads();

  // A staging: 4 instrs/wave; lane -> row wv*32+i*8+(l>>3), lds chunk l&7 holds
  // global chunk (l&7)^(row&7)  [T2 source-side swizzle]
  const unsigned short* aSrc[4];
  int aDst[4];
  int cswz = (lane & 7) ^ ((lane >> 3) & 7);
#pragma unroll
  for (int i = 0; i < 4; ++i) {
    int r = wv * 32 + i * 8 + (lane >> 3);
    aSrc[i] = xb + (size_t)ltok[r] * HD + cswz * 8;
    aDst[i] = (wv * 32 + i * 8) * 64;
  }
  // B staging: 4 instrs/wave; lane -> k-row wv*16+i*4+(l>>4), col chunk (l&15)*4
  const float* bSrc[4];
  int bDst[4];
  {
    int cc = lane & 15;
    int gcol = (cc < 8) ? (c0 + cc * 4) : (ID + c0 + (cc - 8) * 4);
    const float* Wg = gup + (size_t)e * HD * TWO_I;
#pragma unroll
    for (int i = 0; i < 4; ++i) {
      int kr = wv * 16 + i * 4 + (lane >> 4);
      bSrc[i] = Wg + (size_t)kr * TWO_I + gcol;
      bDst[i] = (wv * 16 + i * 4) * 64;
    }
  }

  auto stage = [&](int buf) {
#pragma unroll
    for (int i = 0; i < 4; ++i) { gl_lds16(aSrc[i], &Abuf[buf][aDst[i]]); aSrc[i] += 64; }
#pragma unroll
    for (int i = 0; i < 4; ++i) { gl_lds16(bSrc[i], &Bbuf[buf][bDst[i]]); bSrc[i] += (size_t)64 * TWO_I; }
  };

  stage(0);

  f32x4_t zero = {0.f, 0.f, 0.f, 0.f};
  f32x4_t accg[2][2], accu[2][2];
#pragma unroll
  for (int m = 0; m < 2; ++m)
#pragma unroll
    for (int n = 0; n < 2; ++n) { accg[m][n] = zero; accu[m][n] = zero; }

  int lr = lane & 15, hi = lane >> 4, mb = wv * 32;

  for (int kt = 0; kt < 32; ++kt) {
    int cur = kt & 1;
    if (kt < 31) {
      stage(cur ^ 1);
      asm volatile("s_waitcnt vmcnt(8)" ::: "memory");  // tile kt landed; kt+1 in flight
    } else {
      asm volatile("s_waitcnt vmcnt(0)" ::: "memory");
    }
    __builtin_amdgcn_sched_barrier(0);
    __builtin_amdgcn_s_barrier();

    // transpose+convert B: thread covers col=lane, kseg=wv (16 k's)
    {
      int c = lane, ks = wv;
      unsigned short tmp[16];
#pragma unroll
      for (int j = 0; j < 16; ++j) tmp[j] = f2bf(Bbuf[cur][(ks * 16 + j) * 64 + c]);
      uint4 p0, p1;
      p0.x = pk2(tmp[0], tmp[1]);   p0.y = pk2(tmp[2], tmp[3]);
      p0.z = pk2(tmp[4], tmp[5]);   p0.w = pk2(tmp[6], tmp[7]);
      p1.x = pk2(tmp[8], tmp[9]);   p1.y = pk2(tmp[10], tmp[11]);
      p1.z = pk2(tmp[12], tmp[13]); p1.w = pk2(tmp[14], tmp[15]);
      *(uint4*)&Pbuf[c * PITCH + ks * 16] = p0;
      *(uint4*)&Pbuf[c * PITCH + ks * 16 + 8] = p1;
    }
    asm volatile("s_waitcnt lgkmcnt(0)" ::: "memory");
    __builtin_amdgcn_sched_barrier(0);
    __builtin_amdgcn_s_barrier();

#pragma unroll
    for (int kk = 0; kk < 2; ++kk) {
      int klo = kk * 32 + hi * 8;
      bf16x8_t a[2], bg[2], bu[2];
#pragma unroll
      for (int m = 0; m < 2; ++m) {
        int R = mb + m * 16 + lr;
        int ch = (kk * 4 + hi) ^ (R & 7);
        a[m] = *(bf16x8_t*)&Abuf[cur][R * 64 + ch * 8];
      }
#pragma unroll
      for (int n = 0; n < 2; ++n) {
        bg[n] = *(bf16x8_t*)&Pbuf[(n * 16 + lr) * PITCH + klo];
        bu[n] = *(bf16x8_t*)&Pbuf[(32 + n * 16 + lr) * PITCH + klo];
      }
#pragma unroll
      for (int m = 0; m < 2; ++m)
#pragma unroll
        for (int n = 0; n < 2; ++n) {
          accg[m][n] = __builtin_amdgcn_mfma_f32_16x16x32_bf16(a[m], bg[n], accg[m][n], 0, 0, 0);
          accu[m][n] = __builtin_amdgcn_mfma_f32_16x16x32_bf16(a[m], bu[n], accu[m][n], 0, 0, 0);
        }
    }
    if (kt < 31) __builtin_amdgcn_s_barrier();  // protect cur bufs from next stage
  }

  int rq = hi * 4;
#pragma unroll
  for (int m = 0; m < 2; ++m)
#pragma unroll
    for (int n = 0; n < 2; ++n)
#pragma unroll
      for (int j = 0; j < 4; ++j) {
        int r = tb + mb + m * 16 + rq + j;
        if (r < cnt) {
          float g = accg[m][n][j], u = accu[m][n][j];
          float hv = (g / (1.f + __expf(-g))) * u;
          hbuf[(size_t)(off + r) * ID + c0 + n * 16 + lr] = f2bf(hv);
        }
      }
}

// ---------------- gemm2: out = h @ Wd ----------------
// same async structure; M=128 x 64 out-cols, 8 K-steps
__global__ __launch_bounds__(256, 2) void k_gemm2(
    const unsigned short* __restrict__ hbuf, const float* __restrict__ dwn,
    const int* __restrict__ offsets, const int* __restrict__ tlist,
    const int* __restrict__ wk, float* __restrict__ out) {
  int item = blockIdx.y;
  if (item >= wk[MAXITEMS]) return;
  int w = wk[item];
  int e = w & 255, tb = (w >> 8) * 128;
  int off = offsets[e], cnt = offsets[e + 1] - off;
  int c0 = blockIdx.x * 64;

  __shared__ unsigned short Abuf[2][128 * 64];
  __shared__ float Bbuf[2][64 * 64];
  __shared__ unsigned short Pbuf[64 * PITCH];

  int tid = threadIdx.x, lane = tid & 63, wv = tid >> 6;

  const unsigned short* aSrc[4];
  int aDst[4];
  int cswz = (lane & 7) ^ ((lane >> 3) & 7);
#pragma unroll
  for (int i = 0; i < 4; ++i) {
    int r = tb + wv * 32 + i * 8 + (lane >> 3);
    if (r > cnt - 1) r = cnt - 1;
    aSrc[i] = hbuf + (size_t)(off + r) * ID + cswz * 8;
    aDst[i] = (wv * 32 + i * 8) * 64;
  }
  const float* bSrc[4];
  int bDst[4];
  {
    int cc = lane & 15;
    const float* Wd = dwn + (size_t)e * ID * HD;
#pragma unroll
    for (int i = 0; i < 4; ++i) {
      int kr = wv * 16 + i * 4 + (lane >> 4);
      bSrc[i] = Wd + (size_t)kr * HD + c0 + cc * 4;
      bDst[i] = (wv * 16 + i * 4) * 64;
    }
  }

  auto stage = [&](int buf) {
#pragma unroll
    for (int i = 0; i < 4; ++i) { gl_lds16(aSrc[i], &Abuf[buf][aDst[i]]); aSrc[i] += 64; }
#pragma unroll
    for (int i = 0; i < 4; ++i) { gl_lds16(bSrc[i], &Bbuf[buf][bDst[i]]); bSrc[i] += (size_t)64 * HD; }
  };

  stage(0);

  f32x4_t zero = {0.f, 0.f, 0.f, 0.f};
  f32x4_t acc[2][4];
#pragma unroll
  for (int m = 0; m < 2; ++m)
#pragma unroll
    for (int n = 0; n < 4; ++n) acc[m][n] = zero;

  int lr = lane & 15, hi = lane >> 4, mb = wv * 32;

  for (int kt = 0; kt < 8; ++kt) {
    int cur = kt & 1;
    if (kt < 7) {
      stage(cur ^ 1);
      asm volatile("s_waitcnt vmcnt(8)" ::: "memory");
    } else {
      asm volatile("s_waitcnt vmcnt(0)" ::: "memory");
    }
    __builtin_amdgcn_sched_barrier(0);
    __builtin_amdgcn_s_barrier();

    {
      int c = lane, ks = wv;
      unsigned short tmp[16];
#pragma unroll
      for (int j = 0; j < 16; ++j) tmp[j] = f2bf(Bbuf[cur][(ks * 16 + j) * 64 + c]);
      uint4 p0, p1;
      p0.x = pk2(tmp[0], tmp[1]);   p0.y = pk2(tmp[2], tmp[3]);
      p0.z = pk2(tmp[4], tmp[5]);   p0.w = pk2(tmp[6], tmp[7]);
      p1.x = pk2(tmp[8], tmp[9]);   p1.y = pk2(tmp[10], tmp[11]);
      p1.z = pk2(tmp[12], tmp[13]); p1.w = pk2(tmp[14], tmp[15]);
      *(uint4*)&Pbuf[c * PITCH + ks * 16] = p0;
      *(uint4*)&Pbuf[c * PITCH + ks * 16 + 8] = p1;
    }
    asm volatile("s_waitcnt lgkmcnt(0)" ::: "memory");
    __builtin_amdgcn_sched_barrier(0);
    __builtin_amdgcn_s_barrier();

#pragma unroll
    for (int kk = 0; kk < 2; ++kk) {
      int klo = kk * 32 + hi * 8;
      bf16x8_t a[2], b[4];
#pragma unroll
      for (int m = 0; m < 2; ++m) {
        int R = mb + m * 16 + lr;
        int ch = (kk * 4 + hi) ^ (R & 7);
        a[m] = *(bf16x8_t*)&Abuf[cur][R * 64 + ch * 8];
      }
#pragma unroll
      for (int n = 0; n < 4; ++n) b[n] = *(bf16x8_t*)&Pbuf[(n * 16 + lr) * PITCH + klo];
#pragma unroll
      for (int m = 0; m < 2; ++m)
#pragma unroll
        for (int n = 0; n < 4; ++n)
          acc[m][n] = __builtin_amdgcn_mfma_f32_16x16x32_bf16(a[m], b[n], acc[m][n], 0, 0, 0);
    }
    if (kt < 7) __builtin_amdgcn_s_barrier();
  }

  int rq = hi * 4;
#pragma unroll
  for (int m = 0; m < 2; ++m)
#pragma unroll
    for (int n = 0; n < 4; ++n)
#pragma unroll
      for (int j = 0; j < 4; ++j) {
        int r = tb + mb + m * 16 + rq + j;
        if (r < cnt) {
          out[(size_t)tlist[off + r] * HD + c0 + n * 16 + lr] = acc[m][n][j];
        }
      }
}

extern "C" void kernel_launch(void* const* d_in, const int* in_sizes, int n_in,
                              void* d_out, int out_size, void* d_ws, size_t ws_size,
                              hipStream_t stream) {
  (void)in_sizes; (void)n_in; (void)out_size; (void)ws_size;
  const float* x   = (const float*)d_in[0];
  const int*   tok = (const int*)d_in[1];
  const float* mu  = (const float*)d_in[2];
  const float* gup = (const float*)d_in[3];
  const float* dwn = (const float*)d_in[4];
  const float* wr  = (const float*)d_in[5];
  float* out = (float*)d_out;

  char* ws = (char*)d_ws;
  int* eid     = (int*)ws;
  int* tlist   = (int*)(ws + 16384);
  int* counts  = (int*)(ws + 32768);
  int* offsets = (int*)(ws + 32896);
  int* cursors = (int*)(ws + 33024);
  int* wk      = (int*)(ws + 33152);
  unsigned short* xb   = (unsigned short*)(ws + 65536);
  unsigned short* hbuf = (unsigned short*)(ws + 65536 + (size_t)NT * HD * 2);

  k_cast_x <<<4096, 256, 0, stream>>>(x, xb);
  k_route  <<<NT, 256, 0, stream>>>(mu, tok, wr, eid);
  k_init   <<<1, 64, 0, stream>>>(counts, cursors);
  k_hist   <<<16, 256, 0, stream>>>(eid, counts);
  k_scan   <<<1, 64, 0, stream>>>(counts, offsets, cursors, wk);
  k_scatter<<<16, 256, 0, stream>>>(eid, cursors, tlist);
  k_gemm1  <<<dim3(16, MAXITEMS), 256, 0, stream>>>(xb, gup, offsets, tlist, wk, hbuf);
  k_gemm2  <<<dim3(32, MAXITEMS), 256, 0, stream>>>(hbuf, dwn, offsets, tlist, wk, out);
}

// Round 8
// 202.840 us; speedup vs baseline: 1.0891x; 1.0891x over previous
//
#include <hip/hip_runtime.h>
#include <hip/hip_bf16.h>

#define NT 4096
#define HD 2048
#define NE 16
#define ID 512
#define TWO_I 1024
#define PITCH 72     // padded bf16 P-tile pitch (144B)
#define MAXITEMS 47  // worst case: ceil(4081/128)=32 + 15 singleton experts

typedef __attribute__((ext_vector_type(8))) short bf16x8_t;
typedef __attribute__((ext_vector_type(4))) float f32x4_t;

__device__ __forceinline__ unsigned short f2bf(float f) {
  union { float f; unsigned int u; } v; v.f = f;
  unsigned int r = v.u + 0x7fffu + ((v.u >> 16) & 1u);
  return (unsigned short)(r >> 16);
}
__device__ __forceinline__ unsigned pk2(unsigned short a, unsigned short b) {
  return (unsigned)a | ((unsigned)b << 16);
}
__device__ __forceinline__ void gl_lds16(const void* g, void* l) {
  __builtin_amdgcn_global_load_lds(
      (const __attribute__((address_space(1))) unsigned int*)g,
      (__attribute__((address_space(3))) unsigned int*)l, 16, 0, 0);
}

// ---------------- cast x (f32 -> bf16) ----------------
__global__ void k_cast_x(const float* __restrict__ x, unsigned short* __restrict__ xb) {
  size_t i = ((size_t)blockIdx.x * 256 + threadIdx.x) * 8;
  float4 a = *(const float4*)(x + i);
  float4 b = *(const float4*)(x + i + 4);
  uint4 pk;
  pk.x = pk2(f2bf(a.x), f2bf(a.y)); pk.y = pk2(f2bf(a.z), f2bf(a.w));
  pk.z = pk2(f2bf(b.x), f2bf(b.y)); pk.w = pk2(f2bf(b.z), f2bf(b.w));
  *(uint4*)(xb + i) = pk;
}

// ---------------- routing ----------------
__global__ void k_route(const float* __restrict__ mu, const int* __restrict__ tok,
                        const float* __restrict__ wr, int* __restrict__ eid) {
  int t = blockIdx.x;
  int tid = threadIdx.x;
  float p[NE];
#pragma unroll
  for (int e = 0; e < NE; ++e) p[e] = 0.f;
  const float* m = mu + (size_t)t * HD;
  for (int h = tid; h < HD; h += 256) {
    float mv = m[h];
#pragma unroll
    for (int e = 0; e < NE; ++e) p[e] += mv * wr[e * HD + h];
  }
#pragma unroll
  for (int e = 0; e < NE; ++e) {
    float v = p[e];
#pragma unroll
    for (int s = 32; s; s >>= 1) v += __shfl_xor(v, s, 64);
    p[e] = v;
  }
  __shared__ float red[4][NE];
  int lane = tid & 63, wv = tid >> 6;
  if (lane == 0) {
#pragma unroll
    for (int e = 0; e < NE; ++e) red[wv][e] = p[e];
  }
  __syncthreads();
  if (tid == 0) {
    int tk = tok[t];
    if (tk < 0) tk = 0;
    if (tk > 31999) tk = 31999;
    int base = tk & 15;
    float best = -3.0e38f; int bi = 0;
    for (int e = 0; e < NE; ++e) {
      float v = red[0][e] + red[1][e] + red[2][e] + red[3][e];
      if (e == base) v += 10.0f;
      if (v > best) { best = v; bi = e; }
    }
    eid[t] = bi;
  }
}

// ---------------- bucket tokens + worklist ----------------
__global__ void k_init(int* counts, int* cursors) {
  int i = threadIdx.x;
  if (i < NE) { counts[i] = 0; cursors[i] = 0; }
}
__global__ void k_hist(const int* __restrict__ eid, int* __restrict__ counts) {
  int t = blockIdx.x * 256 + threadIdx.x;
  if (t < NT) atomicAdd(&counts[eid[t]], 1);
}
__global__ void k_scan(const int* __restrict__ counts, int* __restrict__ offsets,
                       int* __restrict__ cursors, int* __restrict__ wk) {
  if (threadIdx.x == 0) {
    int s = 0;
    for (int e = 0; e < NE; ++e) { offsets[e] = s; cursors[e] = s; s += counts[e]; }
    offsets[NE] = s;
    int n = 0;
    for (int e = 0; e < NE; ++e) {
      int tiles = (counts[e] + 127) >> 7;
      for (int m = 0; m < tiles; ++m) { wk[n++] = e | (m << 8); }
    }
    wk[MAXITEMS] = n;
  }
}
__global__ void k_scatter(const int* __restrict__ eid, int* __restrict__ cursors,
                          int* __restrict__ tlist) {
  int t = blockIdx.x * 256 + threadIdx.x;
  if (t < NT) {
    int e = eid[t];
    int pos = atomicAdd(&cursors[e], 1);
    tlist[pos] = t;
  }
}

// ---------------- gemm1: h = silu(x@Wg) * (x@Wu) ----------------
// 2-barrier K-loop: B f32 via async gload_lds (dbuf) + in-LDS transpose/cvt,
// A-frags direct global->reg (xb is L2-resident). M=128, 32 gate + 32 up cols.
__global__ __launch_bounds__(256, 3) void k_gemm1(
    const unsigned short* __restrict__ xb, const float* __restrict__ gup,
    const int* __restrict__ offsets, const int* __restrict__ tlist,
    const int* __restrict__ wk, unsigned short* __restrict__ hbuf) {
  int item = blockIdx.y;
  if (item >= wk[MAXITEMS]) return;
  int w = wk[item];
  int e = w & 255, tb = (w >> 8) * 128;
  int off = offsets[e], cnt = offsets[e + 1] - off;
  int c0 = blockIdx.x * 32;

  __shared__ float Bbuf[2][64 * 64];           // [k][col] f32; cols 0-31 gate, 32-63 up
  __shared__ unsigned short Pbuf[64 * PITCH];  // [col][k] bf16, padded
  __shared__ int ltok[128];

  int tid = threadIdx.x, lane = tid & 63, wv = tid >> 6;
  if (tid < 128) { int r = tb + tid; if (r > cnt - 1) r = cnt - 1; ltok[tid] = tlist[off + r]; }
  __syncthreads();

  int lr = lane & 15, hi = lane >> 4, mb = wv * 32;
  // A row tokens for this thread's two frag rows
  const unsigned short* aRow0 = xb + (size_t)ltok[mb + lr] * HD + hi * 8;
  const unsigned short* aRow1 = xb + (size_t)ltok[mb + 16 + lr] * HD + hi * 8;

  // B staging: 4 gload_lds per wave per K-step
  const float* bSrc[4];
  int bDst[4];
  {
    int cc = lane & 15;
    int gcol = (cc < 8) ? (c0 + cc * 4) : (ID + c0 + (cc - 8) * 4);
    const float* Wg = gup + (size_t)e * HD * TWO_I;
#pragma unroll
    for (int i = 0; i < 4; ++i) {
      int kr = wv * 16 + i * 4 + (lane >> 4);
      bSrc[i] = Wg + (size_t)kr * TWO_I + gcol;
      bDst[i] = (wv * 16 + i * 4) * 64;
    }
  }
  auto stageB = [&](int buf) {
#pragma unroll
    for (int i = 0; i < 4; ++i) { gl_lds16(bSrc[i], &Bbuf[buf][bDst[i]]); bSrc[i] += (size_t)64 * TWO_I; }
  };

  stageB(0);

  f32x4_t zero = {0.f, 0.f, 0.f, 0.f};
  f32x4_t accg[2][2], accu[2][2];
#pragma unroll
  for (int m = 0; m < 2; ++m)
#pragma unroll
    for (int n = 0; n < 2; ++n) { accg[m][n] = zero; accu[m][n] = zero; }

  for (int kt = 0; kt < 32; ++kt) {
    int cur = kt & 1;
    __builtin_amdgcn_s_barrier();             // BARRIER1: prev MFMA (Pbuf reads) done
    // A-frag loads for this K-step (direct to regs; mostly L2 hits)
    bf16x8_t a00, a01, a10, a11;
    a00 = *(const bf16x8_t*)(aRow0 + kt * 64);
    a01 = *(const bf16x8_t*)(aRow0 + kt * 64 + 32);
    a10 = *(const bf16x8_t*)(aRow1 + kt * 64);
    a11 = *(const bf16x8_t*)(aRow1 + kt * 64 + 32);
    __builtin_amdgcn_sched_barrier(0);
    if (kt < 31) stageB(cur ^ 1);             // next tile DMA, in flight across phases
    __builtin_amdgcn_sched_barrier(0);
    if (kt < 31) asm volatile("s_waitcnt vmcnt(4)" ::: "memory");  // drains B(kt)+A(kt)
    else         asm volatile("s_waitcnt vmcnt(0)" ::: "memory");
    __builtin_amdgcn_sched_barrier(0);
    __builtin_amdgcn_s_barrier();             // all waves' B(kt) DMA landed

    // transpose+convert B: thread covers P-col=lane, kseg=wv (16 k's)
    {
      int c = lane, ks = wv;
      unsigned short tmp[16];
#pragma unroll
      for (int j = 0; j < 16; ++j) tmp[j] = f2bf(Bbuf[cur][(ks * 16 + j) * 64 + c]);
      uint4 p0, p1;
      p0.x = pk2(tmp[0], tmp[1]);   p0.y = pk2(tmp[2], tmp[3]);
      p0.z = pk2(tmp[4], tmp[5]);   p0.w = pk2(tmp[6], tmp[7]);
      p1.x = pk2(tmp[8], tmp[9]);   p1.y = pk2(tmp[10], tmp[11]);
      p1.z = pk2(tmp[12], tmp[13]); p1.w = pk2(tmp[14], tmp[15]);
      *(uint4*)&Pbuf[c * PITCH + ks * 16] = p0;
      *(uint4*)&Pbuf[c * PITCH + ks * 16 + 8] = p1;
    }
    asm volatile("s_waitcnt lgkmcnt(0)" ::: "memory");
    __builtin_amdgcn_sched_barrier(0);
    __builtin_amdgcn_s_barrier();             // BARRIER2: Pbuf ready

    __builtin_amdgcn_s_setprio(1);
#pragma unroll
    for (int kk = 0; kk < 2; ++kk) {
      int klo = kk * 32 + hi * 8;
      bf16x8_t bg[2], bu[2];
#pragma unroll
      for (int n = 0; n < 2; ++n) {
        bg[n] = *(bf16x8_t*)&Pbuf[(n * 16 + lr) * PITCH + klo];
        bu[n] = *(bf16x8_t*)&Pbuf[(32 + n * 16 + lr) * PITCH + klo];
      }
      bf16x8_t a0 = kk ? a01 : a00;
      bf16x8_t a1 = kk ? a11 : a10;
#pragma unroll
      for (int n = 0; n < 2; ++n) {
        accg[0][n] = __builtin_amdgcn_mfma_f32_16x16x32_bf16(a0, bg[n], accg[0][n], 0, 0, 0);
        accu[0][n] = __builtin_amdgcn_mfma_f32_16x16x32_bf16(a0, bu[n], accu[0][n], 0, 0, 0);
        accg[1][n] = __builtin_amdgcn_mfma_f32_16x16x32_bf16(a1, bg[n], accg[1][n], 0, 0, 0);
        accu[1][n] = __builtin_amdgcn_mfma_f32_16x16x32_bf16(a1, bu[n], accu[1][n], 0, 0, 0);
      }
    }
    __builtin_amdgcn_s_setprio(0);
  }

  int rq = hi * 4;
#pragma unroll
  for (int m = 0; m < 2; ++m)
#pragma unroll
    for (int n = 0; n < 2; ++n)
#pragma unroll
      for (int j = 0; j < 4; ++j) {
        int r = tb + mb + m * 16 + rq + j;
        if (r < cnt) {
          float g = accg[m][n][j], u = accu[m][n][j];
          float hv = (g / (1.f + __expf(-g))) * u;
          hbuf[(size_t)(off + r) * ID + c0 + n * 16 + lr] = f2bf(hv);
        }
      }
}

// ---------------- gemm2: out = h @ Wd ----------------
// same 2-barrier structure; M=128 x 64 out-cols, 8 K-steps; A direct from hbuf (L2)
__global__ __launch_bounds__(256, 3) void k_gemm2(
    const unsigned short* __restrict__ hbuf, const float* __restrict__ dwn,
    const int* __restrict__ offsets, const int* __restrict__ tlist,
    const int* __restrict__ wk, float* __restrict__ out) {
  int item = blockIdx.y;
  if (item >= wk[MAXITEMS]) return;
  int w = wk[item];
  int e = w & 255, tb = (w >> 8) * 128;
  int off = offsets[e], cnt = offsets[e + 1] - off;
  int c0 = blockIdx.x * 64;

  __shared__ float Bbuf[2][64 * 64];           // [k][col] f32
  __shared__ unsigned short Pbuf[64 * PITCH];  // [col][k] bf16

  int tid = threadIdx.x, lane = tid & 63, wv = tid >> 6;
  int lr = lane & 15, hi = lane >> 4, mb = wv * 32;

  int r0 = tb + mb + lr;      if (r0 > cnt - 1) r0 = cnt - 1;
  int r1 = tb + mb + 16 + lr; if (r1 > cnt - 1) r1 = cnt - 1;
  const unsigned short* aRow0 = hbuf + (size_t)(off + r0) * ID + hi * 8;
  const unsigned short* aRow1 = hbuf + (size_t)(off + r1) * ID + hi * 8;

  const float* bSrc[4];
  int bDst[4];
  {
    int cc = lane & 15;
    const float* Wd = dwn + (size_t)e * ID * HD;
#pragma unroll
    for (int i = 0; i < 4; ++i) {
      int kr = wv * 16 + i * 4 + (lane >> 4);
      bSrc[i] = Wd + (size_t)kr * HD + c0 + cc * 4;
      bDst[i] = (wv * 16 + i * 4) * 64;
    }
  }
  auto stageB = [&](int buf) {
#pragma unroll
    for (int i = 0; i < 4; ++i) { gl_lds16(bSrc[i], &Bbuf[buf][bDst[i]]); bSrc[i] += (size_t)64 * HD; }
  };

  stageB(0);

  f32x4_t zero = {0.f, 0.f, 0.f, 0.f};
  f32x4_t acc[2][4];
#pragma unroll
  for (int m = 0; m < 2; ++m)
#pragma unroll
    for (int n = 0; n < 4; ++n) acc[m][n] = zero;

  for (int kt = 0; kt < 8; ++kt) {
    int cur = kt & 1;
    __builtin_amdgcn_s_barrier();
    bf16x8_t a00, a01, a10, a11;
    a00 = *(const bf16x8_t*)(aRow0 + kt * 64);
    a01 = *(const bf16x8_t*)(aRow0 + kt * 64 + 32);
    a10 = *(const bf16x8_t*)(aRow1 + kt * 64);
    a11 = *(const bf16x8_t*)(aRow1 + kt * 64 + 32);
    __builtin_amdgcn_sched_barrier(0);
    if (kt < 7) stageB(cur ^ 1);
    __builtin_amdgcn_sched_barrier(0);
    if (kt < 7) asm volatile("s_waitcnt vmcnt(4)" ::: "memory");
    else        asm volatile("s_waitcnt vmcnt(0)" ::: "memory");
    __builtin_amdgcn_sched_barrier(0);
    __builtin_amdgcn_s_barrier();

    {
      int c = lane, ks = wv;
      unsigned short tmp[16];
#pragma unroll
      for (int j = 0; j < 16; ++j) tmp[j] = f2bf(Bbuf[cur][(ks * 16 + j) * 64 + c]);
      uint4 p0, p1;
      p0.x = pk2(tmp[0], tmp[1]);   p0.y = pk2(tmp[2], tmp[3]);
      p0.z = pk2(tmp[4], tmp[5]);   p0.w = pk2(tmp[6], tmp[7]);
      p1.x = pk2(tmp[8], tmp[9]);   p1.y = pk2(tmp[10], tmp[11]);
      p1.z = pk2(tmp[12], tmp[13]); p1.w = pk2(tmp[14], tmp[15]);
      *(uint4*)&Pbuf[c * PITCH + ks * 16] = p0;
      *(uint4*)&Pbuf[c * PITCH + ks * 16 + 8] = p1;
    }
    asm volatile("s_waitcnt lgkmcnt(0)" ::: "memory");
    __builtin_amdgcn_sched_barrier(0);
    __builtin_amdgcn_s_barrier();

    __builtin_amdgcn_s_setprio(1);
#pragma unroll
    for (int kk = 0; kk < 2; ++kk) {
      int klo = kk * 32 + hi * 8;
      bf16x8_t b[4];
#pragma unroll
      for (int n = 0; n < 4; ++n) b[n] = *(bf16x8_t*)&Pbuf[(n * 16 + lr) * PITCH + klo];
      bf16x8_t a0 = kk ? a01 : a00;
      bf16x8_t a1 = kk ? a11 : a10;
#pragma unroll
      for (int n = 0; n < 4; ++n) {
        acc[0][n] = __builtin_amdgcn_mfma_f32_16x16x32_bf16(a0, b[n], acc[0][n], 0, 0, 0);
        acc[1][n] = __builtin_amdgcn_mfma_f32_16x16x32_bf16(a1, b[n], acc[1][n], 0, 0, 0);
      }
    }
    __builtin_amdgcn_s_setprio(0);
  }

  int rq = hi * 4;
#pragma unroll
  for (int m = 0; m < 2; ++m)
#pragma unroll
    for (int n = 0; n < 4; ++n)
#pragma unroll
      for (int j = 0; j < 4; ++j) {
        int r = tb + mb + m * 16 + rq + j;
        if (r < cnt) {
          out[(size_t)tlist[off + r] * HD + c0 + n * 16 + lr] = acc[m][n][j];
        }
      }
}

extern "C" void kernel_launch(void* const* d_in, const int* in_sizes, int n_in,
                              void* d_out, int out_size, void* d_ws, size_t ws_size,
                              hipStream_t stream) {
  (void)in_sizes; (void)n_in; (void)out_size; (void)ws_size;
  const float* x   = (const float*)d_in[0];
  const int*   tok = (const int*)d_in[1];
  const float* mu  = (const float*)d_in[2];
  const float* gup = (const float*)d_in[3];
  const float* dwn = (const float*)d_in[4];
  const float* wr  = (const float*)d_in[5];
  float* out = (float*)d_out;

  char* ws = (char*)d_ws;
  int* eid     = (int*)ws;
  int* tlist   = (int*)(ws + 16384);
  int* counts  = (int*)(ws + 32768);
  int* offsets = (int*)(ws + 32896);
  int* cursors = (int*)(ws + 33024);
  int* wk      = (int*)(ws + 33152);
  unsigned short* xb   = (unsigned short*)(ws + 65536);
  unsigned short* hbuf = (unsigned short*)(ws + 65536 + (size_t)NT * HD * 2);

  k_cast_x <<<4096, 256, 0, stream>>>(x, xb);
  k_route  <<<NT, 256, 0, stream>>>(mu, tok, wr, eid);
  k_init   <<<1, 64, 0, stream>>>(counts, cursors);
  k_hist   <<<16, 256, 0, stream>>>(eid, counts);
  k_scan   <<<1, 64, 0, stream>>>(counts, offsets, cursors, wk);
  k_scatter<<<16, 256, 0, stream>>>(eid, cursors, tlist);
  k_gemm1  <<<dim3(16, MAXITEMS), 256, 0, stream>>>(xb, gup, offsets, tlist, wk, hbuf);
  k_gemm2  <<<dim3(32, MAXITEMS), 256, 0, stream>>>(hbuf, dwn, offsets, tlist, wk, out);
}

// Round 9
// 201.252 us; speedup vs baseline: 1.0977x; 1.0079x over previous
//
#include <hip/hip_runtime.h>
#include <hip/hip_bf16.h>

#define NT 4096
#define HD 2048
#define NE 16
#define ID 512
#define TWO_I 1024
#define PITCH 72     // padded bf16 P-tile pitch (144B)
#define MAXITEMS 47  // worst case: ceil(4081/128)=32 + 15 singleton experts

typedef __attribute__((ext_vector_type(8))) short bf16x8_t;
typedef __attribute__((ext_vector_type(4))) float f32x4_t;

__device__ __forceinline__ unsigned short f2bf(float f) {
  union { float f; unsigned int u; } v; v.f = f;
  unsigned int r = v.u + 0x7fffu + ((v.u >> 16) & 1u);
  return (unsigned short)(r >> 16);
}
__device__ __forceinline__ unsigned pk2(unsigned short a, unsigned short b) {
  return (unsigned)a | ((unsigned)b << 16);
}
__device__ __forceinline__ void gl_lds16(const void* g, void* l) {
  __builtin_amdgcn_global_load_lds(
      (const __attribute__((address_space(1))) unsigned int*)g,
      (__attribute__((address_space(3))) unsigned int*)l, 16, 0, 0);
}

// ---------------- cast x (f32 -> bf16) ----------------
__global__ void k_cast_x(const float* __restrict__ x, unsigned short* __restrict__ xb) {
  size_t i = ((size_t)blockIdx.x * 256 + threadIdx.x) * 8;
  float4 a = *(const float4*)(x + i);
  float4 b = *(const float4*)(x + i + 4);
  uint4 pk;
  pk.x = pk2(f2bf(a.x), f2bf(a.y)); pk.y = pk2(f2bf(a.z), f2bf(a.w));
  pk.z = pk2(f2bf(b.x), f2bf(b.y)); pk.w = pk2(f2bf(b.z), f2bf(b.w));
  *(uint4*)(xb + i) = pk;
}

// ---------------- routing ----------------
__global__ void k_route(const float* __restrict__ mu, const int* __restrict__ tok,
                        const float* __restrict__ wr, int* __restrict__ eid) {
  int t = blockIdx.x;
  int tid = threadIdx.x;
  float p[NE];
#pragma unroll
  for (int e = 0; e < NE; ++e) p[e] = 0.f;
  const float* m = mu + (size_t)t * HD;
  for (int h = tid; h < HD; h += 256) {
    float mv = m[h];
#pragma unroll
    for (int e = 0; e < NE; ++e) p[e] += mv * wr[e * HD + h];
  }
#pragma unroll
  for (int e = 0; e < NE; ++e) {
    float v = p[e];
#pragma unroll
    for (int s = 32; s; s >>= 1) v += __shfl_xor(v, s, 64);
    p[e] = v;
  }
  __shared__ float red[4][NE];
  int lane = tid & 63, wv = tid >> 6;
  if (lane == 0) {
#pragma unroll
    for (int e = 0; e < NE; ++e) red[wv][e] = p[e];
  }
  __syncthreads();
  if (tid == 0) {
    int tk = tok[t];
    if (tk < 0) tk = 0;
    if (tk > 31999) tk = 31999;
    int base = tk & 15;
    float best = -3.0e38f; int bi = 0;
    for (int e = 0; e < NE; ++e) {
      float v = red[0][e] + red[1][e] + red[2][e] + red[3][e];
      if (e == base) v += 10.0f;
      if (v > best) { best = v; bi = e; }
    }
    eid[t] = bi;
  }
}

// ---------------- bucket tokens + worklist ----------------
__global__ void k_init(int* counts, int* cursors) {
  int i = threadIdx.x;
  if (i < NE) { counts[i] = 0; cursors[i] = 0; }
}
__global__ void k_hist(const int* __restrict__ eid, int* __restrict__ counts) {
  int t = blockIdx.x * 256 + threadIdx.x;
  if (t < NT) atomicAdd(&counts[eid[t]], 1);
}
__global__ void k_scan(const int* __restrict__ counts, int* __restrict__ offsets,
                       int* __restrict__ cursors, int* __restrict__ wk) {
  if (threadIdx.x == 0) {
    int s = 0;
    for (int e = 0; e < NE; ++e) { offsets[e] = s; cursors[e] = s; s += counts[e]; }
    offsets[NE] = s;
    int n = 0;
    for (int e = 0; e < NE; ++e) {
      int tiles = (counts[e] + 127) >> 7;
      for (int m = 0; m < tiles; ++m) { wk[n++] = e | (m << 8); }
    }
    wk[MAXITEMS] = n;
  }
}
__global__ void k_scatter(const int* __restrict__ eid, int* __restrict__ cursors,
                          int* __restrict__ tlist) {
  int t = blockIdx.x * 256 + threadIdx.x;
  if (t < NT) {
    int e = eid[t];
    int pos = atomicAdd(&cursors[e], 1);
    tlist[pos] = t;
  }
}

// ---------------- gemm1: h = silu(x@Wg) * (x@Wu) ----------------
// 1-barrier K-loop: dbuf Bbuf (DMA) + dbuf Pbuf (transposed bf16) + double-set
// A-regs, everything prefetched one K-step deep, steady-state vmcnt(8).
// Each wave transposes exactly the Bbuf rows it staged -> no Bbuf barrier.
__global__ __launch_bounds__(256, 3) void k_gemm1(
    const unsigned short* __restrict__ xb, const float* __restrict__ gup,
    const int* __restrict__ offsets, const int* __restrict__ tlist,
    const int* __restrict__ wk, unsigned short* __restrict__ hbuf) {
  int item = blockIdx.y;
  if (item >= wk[MAXITEMS]) return;
  int w = wk[item];
  int e = w & 255, tb = (w >> 8) * 128;
  int off = offsets[e], cnt = offsets[e + 1] - off;
  int c0 = blockIdx.x * 32;

  __shared__ float Bbuf[2][64 * 64];              // [k][col] f32; cols 0-31 gate, 32-63 up
  __shared__ unsigned short Pbuf[2][64 * PITCH];  // [col][k] bf16, padded
  __shared__ int ltok[128];

  int tid = threadIdx.x, lane = tid & 63, wv = tid >> 6;  // 4 waves
  if (tid < 128) { int r = tb + tid; if (r > cnt - 1) r = cnt - 1; ltok[tid] = tlist[off + r]; }
  __syncthreads();

  int lr = lane & 15, hi = lane >> 4, mb = wv * 32;
  const unsigned short* aRow0 = xb + (size_t)ltok[mb + lr] * HD + hi * 8;
  const unsigned short* aRow1 = xb + (size_t)ltok[mb + 16 + lr] * HD + hi * 8;

  // B staging: wave wv owns k-rows wv*16..wv*16+15 (4 gl_lds, 4 rows each)
  const float* bSrc[4];
  int bDst[4];
  {
    int cc = lane & 15;
    int gcol = (cc < 8) ? (c0 + cc * 4) : (ID + c0 + (cc - 8) * 4);
    const float* Wg = gup + (size_t)e * HD * TWO_I;
#pragma unroll
    for (int i = 0; i < 4; ++i) {
      int kr = wv * 16 + i * 4 + (lane >> 4);
      bSrc[i] = Wg + (size_t)kr * TWO_I + gcol;
      bDst[i] = (wv * 16 + i * 4) * 64;
    }
  }

#define STAGEB(BUF) do { \
  _Pragma("unroll") for (int i = 0; i < 4; ++i) { \
    gl_lds16(bSrc[i], &Bbuf[BUF][bDst[i]]); bSrc[i] += (size_t)64 * TWO_I; } \
} while (0)

  bf16x8_t A0[4], A1[4];
#define LOADA(SET, KT) do { \
  SET[0] = *(const bf16x8_t*)(aRow0 + (KT) * 64); \
  SET[1] = *(const bf16x8_t*)(aRow0 + (KT) * 64 + 32); \
  SET[2] = *(const bf16x8_t*)(aRow1 + (KT) * 64); \
  SET[3] = *(const bf16x8_t*)(aRow1 + (KT) * 64 + 32); \
} while (0)

#define TRANSP(BUF) do { \
  const float* s_ = &Bbuf[BUF][(wv * 16) * 64 + lane]; \
  unsigned short t_[16]; \
  _Pragma("unroll") for (int j = 0; j < 16; ++j) t_[j] = f2bf(s_[j * 64]); \
  uint4 q0_, q1_; \
  q0_.x = pk2(t_[0], t_[1]);   q0_.y = pk2(t_[2], t_[3]); \
  q0_.z = pk2(t_[4], t_[5]);   q0_.w = pk2(t_[6], t_[7]); \
  q1_.x = pk2(t_[8], t_[9]);   q1_.y = pk2(t_[10], t_[11]); \
  q1_.z = pk2(t_[12], t_[13]); q1_.w = pk2(t_[14], t_[15]); \
  *(uint4*)&Pbuf[BUF][lane * PITCH + wv * 16] = q0_; \
  *(uint4*)&Pbuf[BUF][lane * PITCH + wv * 16 + 8] = q1_; \
} while (0)

  f32x4_t zero = {0.f, 0.f, 0.f, 0.f};
  f32x4_t accg[2][2], accu[2][2];
#pragma unroll
  for (int m = 0; m < 2; ++m)
#pragma unroll
    for (int n = 0; n < 2; ++n) { accg[m][n] = zero; accu[m][n] = zero; }

#define MFMA_PH(BUF, SET) do { \
  __builtin_amdgcn_s_setprio(1); \
  _Pragma("unroll") for (int kk = 0; kk < 2; ++kk) { \
    int klo = kk * 32 + hi * 8; \
    bf16x8_t bg0 = *(bf16x8_t*)&Pbuf[BUF][(lr) * PITCH + klo]; \
    bf16x8_t bg1 = *(bf16x8_t*)&Pbuf[BUF][(16 + lr) * PITCH + klo]; \
    bf16x8_t bu0 = *(bf16x8_t*)&Pbuf[BUF][(32 + lr) * PITCH + klo]; \
    bf16x8_t bu1 = *(bf16x8_t*)&Pbuf[BUF][(48 + lr) * PITCH + klo]; \
    bf16x8_t a0 = SET[kk], a1 = SET[2 + kk]; \
    accg[0][0] = __builtin_amdgcn_mfma_f32_16x16x32_bf16(a0, bg0, accg[0][0], 0, 0, 0); \
    accg[0][1] = __builtin_amdgcn_mfma_f32_16x16x32_bf16(a0, bg1, accg[0][1], 0, 0, 0); \
    accu[0][0] = __builtin_amdgcn_mfma_f32_16x16x32_bf16(a0, bu0, accu[0][0], 0, 0, 0); \
    accu[0][1] = __builtin_amdgcn_mfma_f32_16x16x32_bf16(a0, bu1, accu[0][1], 0, 0, 0); \
    accg[1][0] = __builtin_amdgcn_mfma_f32_16x16x32_bf16(a1, bg0, accg[1][0], 0, 0, 0); \
    accg[1][1] = __builtin_amdgcn_mfma_f32_16x16x32_bf16(a1, bg1, accg[1][1], 0, 0, 0); \
    accu[1][0] = __builtin_amdgcn_mfma_f32_16x16x32_bf16(a1, bu0, accu[1][0], 0, 0, 0); \
    accu[1][1] = __builtin_amdgcn_mfma_f32_16x16x32_bf16(a1, bu1, accu[1][1], 0, 0, 0); \
  } \
  __builtin_amdgcn_s_setprio(0); \
} while (0)

#define SUBSTEP(KT, BUF, SET, VMC) do { \
  asm volatile("s_waitcnt vmcnt(" #VMC ")" ::: "memory"); \
  __builtin_amdgcn_sched_barrier(0); \
  TRANSP(BUF); \
  asm volatile("s_waitcnt lgkmcnt(0)" ::: "memory"); \
  __builtin_amdgcn_sched_barrier(0); \
  __builtin_amdgcn_s_barrier(); \
  MFMA_PH(BUF, SET); \
  if ((KT) + 2 < 32) { LOADA(SET, (KT) + 2); STAGEB(BUF); } \
} while (0)

  // prologue: prefetch steps 0 and 1
  LOADA(A0, 0); STAGEB(0);
  LOADA(A1, 1); STAGEB(1);

  for (int kt2 = 0; kt2 < 15; ++kt2) {
    SUBSTEP(2 * kt2, 0, A0, 8);
    SUBSTEP(2 * kt2 + 1, 1, A1, 8);
  }
  SUBSTEP(30, 0, A0, 8);
  SUBSTEP(31, 1, A1, 0);

#undef SUBSTEP
#undef MFMA_PH
#undef TRANSP
#undef LOADA
#undef STAGEB

  int rq = hi * 4;
#pragma unroll
  for (int m = 0; m < 2; ++m)
#pragma unroll
    for (int n = 0; n < 2; ++n)
#pragma unroll
      for (int j = 0; j < 4; ++j) {
        int r = tb + mb + m * 16 + rq + j;
        if (r < cnt) {
          float g = accg[m][n][j], u = accu[m][n][j];
          float hv = (g / (1.f + __expf(-g))) * u;
          hbuf[(size_t)(off + r) * ID + c0 + n * 16 + lr] = f2bf(hv);
        }
      }
}

// ---------------- gemm2: out = h @ Wd ----------------
// same 1-barrier structure; 8 K-steps; A direct from hbuf (L2-resident)
__global__ __launch_bounds__(256, 3) void k_gemm2(
    const unsigned short* __restrict__ hbuf, const float* __restrict__ dwn,
    const int* __restrict__ offsets, const int* __restrict__ tlist,
    const int* __restrict__ wk, float* __restrict__ out) {
  int item = blockIdx.y;
  if (item >= wk[MAXITEMS]) return;
  int w = wk[item];
  int e = w & 255, tb = (w >> 8) * 128;
  int off = offsets[e], cnt = offsets[e + 1] - off;
  int c0 = blockIdx.x * 64;

  __shared__ float Bbuf[2][64 * 64];
  __shared__ unsigned short Pbuf[2][64 * PITCH];

  int tid = threadIdx.x, lane = tid & 63, wv = tid >> 6;
  int lr = lane & 15, hi = lane >> 4, mb = wv * 32;

  int r0 = tb + mb + lr;      if (r0 > cnt - 1) r0 = cnt - 1;
  int r1 = tb + mb + 16 + lr; if (r1 > cnt - 1) r1 = cnt - 1;
  const unsigned short* aRow0 = hbuf + (size_t)(off + r0) * ID + hi * 8;
  const unsigned short* aRow1 = hbuf + (size_t)(off + r1) * ID + hi * 8;

  const float* bSrc[4];
  int bDst[4];
  {
    int cc = lane & 15;
    const float* Wd = dwn + (size_t)e * ID * HD;
#pragma unroll
    for (int i = 0; i < 4; ++i) {
      int kr = wv * 16 + i * 4 + (lane >> 4);
      bSrc[i] = Wd + (size_t)kr * HD + c0 + cc * 4;
      bDst[i] = (wv * 16 + i * 4) * 64;
    }
  }

#define STAGEB(BUF) do { \
  _Pragma("unroll") for (int i = 0; i < 4; ++i) { \
    gl_lds16(bSrc[i], &Bbuf[BUF][bDst[i]]); bSrc[i] += (size_t)64 * HD; } \
} while (0)

  bf16x8_t A0[4], A1[4];
#define LOADA(SET, KT) do { \
  SET[0] = *(const bf16x8_t*)(aRow0 + (KT) * 64); \
  SET[1] = *(const bf16x8_t*)(aRow0 + (KT) * 64 + 32); \
  SET[2] = *(const bf16x8_t*)(aRow1 + (KT) * 64); \
  SET[3] = *(const bf16x8_t*)(aRow1 + (KT) * 64 + 32); \
} while (0)

#define TRANSP(BUF) do { \
  const float* s_ = &Bbuf[BUF][(wv * 16) * 64 + lane]; \
  unsigned short t_[16]; \
  _Pragma("unroll") for (int j = 0; j < 16; ++j) t_[j] = f2bf(s_[j * 64]); \
  uint4 q0_, q1_; \
  q0_.x = pk2(t_[0], t_[1]);   q0_.y = pk2(t_[2], t_[3]); \
  q0_.z = pk2(t_[4], t_[5]);   q0_.w = pk2(t_[6], t_[7]); \
  q1_.x = pk2(t_[8], t_[9]);   q1_.y = pk2(t_[10], t_[11]); \
  q1_.z = pk2(t_[12], t_[13]); q1_.w = pk2(t_[14], t_[15]); \
  *(uint4*)&Pbuf[BUF][lane * PITCH + wv * 16] = q0_; \
  *(uint4*)&Pbuf[BUF][lane * PITCH + wv * 16 + 8] = q1_; \
} while (0)

  f32x4_t zero = {0.f, 0.f, 0.f, 0.f};
  f32x4_t acc[2][4];
#pragma unroll
  for (int m = 0; m < 2; ++m)
#pragma unroll
    for (int n = 0; n < 4; ++n) acc[m][n] = zero;

#define MFMA_PH(BUF, SET) do { \
  __builtin_amdgcn_s_setprio(1); \
  _Pragma("unroll") for (int kk = 0; kk < 2; ++kk) { \
    int klo = kk * 32 + hi * 8; \
    bf16x8_t b0 = *(bf16x8_t*)&Pbuf[BUF][(lr) * PITCH + klo]; \
    bf16x8_t b1 = *(bf16x8_t*)&Pbuf[BUF][(16 + lr) * PITCH + klo]; \
    bf16x8_t b2 = *(bf16x8_t*)&Pbuf[BUF][(32 + lr) * PITCH + klo]; \
    bf16x8_t b3 = *(bf16x8_t*)&Pbuf[BUF][(48 + lr) * PITCH + klo]; \
    bf16x8_t a0 = SET[kk], a1 = SET[2 + kk]; \
    acc[0][0] = __builtin_amdgcn_mfma_f32_16x16x32_bf16(a0, b0, acc[0][0], 0, 0, 0); \
    acc[0][1] = __builtin_amdgcn_mfma_f32_16x16x32_bf16(a0, b1, acc[0][1], 0, 0, 0); \
    acc[0][2] = __builtin_amdgcn_mfma_f32_16x16x32_bf16(a0, b2, acc[0][2], 0, 0, 0); \
    acc[0][3] = __builtin_amdgcn_mfma_f32_16x16x32_bf16(a0, b3, acc[0][3], 0, 0, 0); \
    acc[1][0] = __builtin_amdgcn_mfma_f32_16x16x32_bf16(a1, b0, acc[1][0], 0, 0, 0); \
    acc[1][1] = __builtin_amdgcn_mfma_f32_16x16x32_bf16(a1, b1, acc[1][1], 0, 0, 0); \
    acc[1][2] = __builtin_amdgcn_mfma_f32_16x16x32_bf16(a1, b2, acc[1][2], 0, 0, 0); \
    acc[1][3] = __builtin_amdgcn_mfma_f32_16x16x32_bf16(a1, b3, acc[1][3], 0, 0, 0); \
  } \
  __builtin_amdgcn_s_setprio(0); \
} while (0)

#define SUBSTEP(KT, BUF, SET, VMC) do { \
  asm volatile("s_waitcnt vmcnt(" #VMC ")" ::: "memory"); \
  __builtin_amdgcn_sched_barrier(0); \
  TRANSP(BUF); \
  asm volatile("s_waitcnt lgkmcnt(0)" ::: "memory"); \
  __builtin_amdgcn_sched_barrier(0); \
  __builtin_amdgcn_s_barrier(); \
  MFMA_PH(BUF, SET); \
  if ((KT) + 2 < 8) { LOADA(SET, (KT) + 2); STAGEB(BUF); } \
} while (0)

  LOADA(A0, 0); STAGEB(0);
  LOADA(A1, 1); STAGEB(1);

  SUBSTEP(0, 0, A0, 8);
  SUBSTEP(1, 1, A1, 8);
  SUBSTEP(2, 0, A0, 8);
  SUBSTEP(3, 1, A1, 8);
  SUBSTEP(4, 0, A0, 8);
  SUBSTEP(5, 1, A1, 8);
  SUBSTEP(6, 0, A0, 8);
  SUBSTEP(7, 1, A1, 0);

#undef SUBSTEP
#undef MFMA_PH
#undef TRANSP
#undef LOADA
#undef STAGEB

  int rq = hi * 4;
#pragma unroll
  for (int m = 0; m < 2; ++m)
#pragma unroll
    for (int n = 0; n < 4; ++n)
#pragma unroll
      for (int j = 0; j < 4; ++j) {
        int r = tb + mb + m * 16 + rq + j;
        if (r < cnt) {
          out[(size_t)tlist[off + r] * HD + c0 + n * 16 + lr] = acc[m][n][j];
        }
      }
}

extern "C" void kernel_launch(void* const* d_in, const int* in_sizes, int n_in,
                              void* d_out, int out_size, void* d_ws, size_t ws_size,
                              hipStream_t stream) {
  (void)in_sizes; (void)n_in; (void)out_size; (void)ws_size;
  const float* x   = (const float*)d_in[0];
  const int*   tok = (const int*)d_in[1];
  const float* mu  = (const float*)d_in[2];
  const float* gup = (const float*)d_in[3];
  const float* dwn = (const float*)d_in[4];
  const float* wr  = (const float*)d_in[5];
  float* out = (float*)d_out;

  char* ws = (char*)d_ws;
  int* eid     = (int*)ws;
  int* tlist   = (int*)(ws + 16384);
  int* counts  = (int*)(ws + 32768);
  int* offsets = (int*)(ws + 32896);
  int* cursors = (int*)(ws + 33024);
  int* wk      = (int*)(ws + 33152);
  unsigned short* xb   = (unsigned short*)(ws + 65536);
  unsigned short* hbuf = (unsigned short*)(ws + 65536 + (size_t)NT * HD * 2);

  k_cast_x <<<4096, 256, 0, stream>>>(x, xb);
  k_route  <<<NT, 256, 0, stream>>>(mu, tok, wr, eid);
  k_init   <<<1, 64, 0, stream>>>(counts, cursors);
  k_hist   <<<16, 256, 0, stream>>>(eid, counts);
  k_scan   <<<1, 64, 0, stream>>>(counts, offsets, cursors, wk);
  k_scatter<<<16, 256, 0, stream>>>(eid, cursors, tlist);
  k_gemm1  <<<dim3(16, MAXITEMS), 256, 0, stream>>>(xb, gup, offsets, tlist, wk, hbuf);
  k_gemm2  <<<dim3(32, MAXITEMS), 256, 0, stream>>>(hbuf, dwn, offsets, tlist, wk, out);
}